// Round 1
// baseline (1055.489 us; speedup 1.0000x reference)
//
#include <hip/hip_runtime.h>

// FeatureExtractor: x[32,512,128,25] --Linear(25->20)+LeakyReLU--> p
//                   --Linear(20->75)--> gx --GRU(H=25, T=128)--> h_T [32,512,25]
// N = 32*512 = 16384 independent sequences.
//
// Mapping: 25-thread "team" per sequence (one thread per hidden unit),
// 10 teams per 256-thread block (250 active). Weights in LDS (bank-conflict-
// free strides), h double-buffered in LDS, x prefetched one step ahead.

#define TT 128
#define CC 25
#define PP 20
#define HH 25
#define G3 75
#define TEAMS 10
#define NSEQ 16384

#define W1_S 25   // [20][25]  gcd(25,32)=1 -> conflict-free across roles
#define WIH_S 21  // [75][21]  gcd(21,32)=1 -> conflict-free (packed 20 would be 8 banks)
#define WHH_S 25  // [75][25]
#define P_S  21   // per-team p stride

__global__ __launch_bounds__(256) void gru_fused(
    const float* __restrict__ x,   const float* __restrict__ W1,
    const float* __restrict__ b1,  const float* __restrict__ Wih,
    const float* __restrict__ Whh, const float* __restrict__ bih,
    const float* __restrict__ bhh, float* __restrict__ out)
{
    __shared__ float sW1[PP * W1_S];
    __shared__ float sWih[G3 * WIH_S];
    __shared__ float sWhh[G3 * WHH_S];
    __shared__ float sb1[PP];
    __shared__ float sx[TEAMS * CC];
    __shared__ float sp[TEAMS * P_S];
    __shared__ float sh[2][TEAMS * HH];

    const int tid = threadIdx.x;

    // ---- cooperative weight staging ----
    for (int idx = tid; idx < PP * CC; idx += 256) {
        int r = idx / CC, c = idx - r * CC;
        sW1[r * W1_S + c] = W1[idx];
    }
    for (int idx = tid; idx < G3 * PP; idx += 256) {
        int r = idx / PP, c = idx - r * PP;
        sWih[r * WIH_S + c] = Wih[idx];
    }
    for (int idx = tid; idx < G3 * HH; idx += 256) {
        sWhh[idx] = Whh[idx];                      // stride 25 packed
    }
    if (tid < PP) sb1[tid] = b1[tid];
    for (int idx = tid; idx < TEAMS * HH; idx += 256) {
        sh[0][idx] = 0.f;
        sh[1][idx] = 0.f;
    }

    const int g = tid / 25;          // team within block
    const int i = tid - g * 25;      // role: hidden unit index
    const int n = blockIdx.x * TEAMS + g;
    const bool active = (g < TEAMS) && (n < NSEQ);

    float bih_r = 0.f, bih_z = 0.f, bih_n = 0.f;
    float bhh_r = 0.f, bhh_z = 0.f, bhh_n = 0.f;
    if (active) {
        bih_r = bih[i]; bih_z = bih[25 + i]; bih_n = bih[50 + i];
        bhh_r = bhh[i]; bhh_z = bhh[25 + i]; bhh_n = bhh[50 + i];
    }

    const float* xp = x + (size_t)(active ? n : 0) * (TT * CC);
    float h_i = 0.f;
    float xv = active ? xp[i] : 0.f;   // prefetched x[n, t=0, i]

    __syncthreads();   // weights + h-init visible

    int cur = 0;
    for (int t = 0; t < TT; ++t) {
        // stage x[n,t,:] (one element per role)
        if (active) sx[g * CC + i] = xv;
        __syncthreads();

        // prefetch next timestep's x while computing
        if (active && (t + 1 < TT)) xv = xp[(t + 1) * CC + i];

        // projection: p = LeakyReLU(W1 @ x + b1), roles 0..19
        if (active && i < PP) {
            float acc = sb1[i];
            #pragma unroll
            for (int c = 0; c < CC; ++c)
                acc += sW1[i * W1_S + c] * sx[g * CC + c];
            acc = (acc >= 0.f) ? acc : 0.01f * acc;
            sp[g * P_S + i] = acc;
        }
        __syncthreads();

        if (active) {
            // input-side gates
            float xr = bih_r, xz = bih_z, xn = bih_n;
            #pragma unroll
            for (int p = 0; p < PP; ++p) {
                const float pv = sp[g * P_S + p];
                xr += sWih[(     i) * WIH_S + p] * pv;
                xz += sWih[(25 + i) * WIH_S + p] * pv;
                xn += sWih[(50 + i) * WIH_S + p] * pv;
            }
            // hidden-side gates
            float hr = bhh_r, hz = bhh_z, hn = bhh_n;
            #pragma unroll
            for (int j = 0; j < HH; ++j) {
                const float hv = sh[cur][g * HH + j];
                hr += sWhh[(     i) * WHH_S + j] * hv;
                hz += sWhh[(25 + i) * WHH_S + j] * hv;
                hn += sWhh[(50 + i) * WHH_S + j] * hv;
            }
            const float r = 1.f / (1.f + __expf(-(xr + hr)));
            const float z = 1.f / (1.f + __expf(-(xz + hz)));
            const float a = xn + r * hn;
            const float nn = 2.f / (1.f + __expf(-2.f * a)) - 1.f;  // tanh(a)
            const float hnew = (1.f - z) * nn + z * h_i;
            h_i = hnew;
            sh[cur ^ 1][g * HH + i] = hnew;
        }
        cur ^= 1;
        // NOTE: no trailing barrier needed — next iteration's two barriers
        // order the sh[] write before the next gate-phase read, and sp/sx
        // rewrites are each separated from this iteration's reads by a barrier.
    }

    if (active) out[(size_t)n * HH + i] = h_i;
}

extern "C" void kernel_launch(void* const* d_in, const int* in_sizes, int n_in,
                              void* d_out, int out_size, void* d_ws, size_t ws_size,
                              hipStream_t stream) {
    const float* x   = (const float*)d_in[0];
    const float* W1  = (const float*)d_in[1];
    const float* b1  = (const float*)d_in[2];
    const float* Wih = (const float*)d_in[3];
    const float* Whh = (const float*)d_in[4];
    const float* bih = (const float*)d_in[5];
    const float* bhh = (const float*)d_in[6];
    float* out = (float*)d_out;

    const int nblocks = (NSEQ + TEAMS - 1) / TEAMS;   // 1639
    gru_fused<<<nblocks, 256, 0, stream>>>(x, W1, b1, Wih, Whh, bih, bhh, out);
}

// Round 2
// 836.066 us; speedup vs baseline: 1.2624x; 1.2624x over previous
//
#include <hip/hip_runtime.h>

// FeatureExtractor: x[32,512,128,25] --Linear(25->20)+LeakyReLU--> p
//                   --Linear(20->75)--> gx --GRU(H=25, T=128)--> h_T [32,512,25]
// N = 32*512 = 16384 independent sequences.
//
// R2: 25-thread team per sequence (thread = hidden unit i), 10 teams / 256-block.
// Gate weights (Wih rows i,i+25,i+50; Whh rows i,i+25,i+50) live in REGISTERS
// (loaded once, L2-cached) instead of being re-read from LDS every timestep.
// Remaining LDS traffic (x/p/h rows) vectorized as float4 from 16B-aligned rows.
// LDS instrs/thread/step: ~225 -> ~29. VALU-issue-bound target.

#define TT 128
#define CC 25
#define PP 20
#define HH 25
#define TEAMS 10
#define NSEQ 16384

// LDS row strides (floats). All row byte-offsets are 16B-aligned.
#define XS 28   // x rows: 112 B
#define PS 20   // p rows: 80 B
#define HS 28   // h rows: 112 B
#define W1S 28  // W1 rows: 112 B

__global__ __launch_bounds__(256, 2) void gru_fused(
    const float* __restrict__ x,   const float* __restrict__ W1,
    const float* __restrict__ b1,  const float* __restrict__ Wih,
    const float* __restrict__ Whh, const float* __restrict__ bih,
    const float* __restrict__ bhh, float* __restrict__ out)
{
    __shared__ __align__(16) float sW1[PP * W1S];
    __shared__ float sb1[PP];
    __shared__ __align__(16) float sx[TEAMS * XS];
    __shared__ __align__(16) float sp[TEAMS * PS];
    __shared__ __align__(16) float sh[2][TEAMS * HS];

    const int tid = threadIdx.x;

    // ---- stage W1 (broadcast-read later), zero h buffers ----
    for (int idx = tid; idx < PP * W1S; idx += 256) sW1[idx] = 0.f;
    for (int idx = tid; idx < TEAMS * HS; idx += 256) {
        sh[0][idx] = 0.f;
        sh[1][idx] = 0.f;
    }
    if (tid < PP) sb1[tid] = b1[tid];
    __syncthreads();  // sW1 zero-fill before scatter of real values
    for (int idx = tid; idx < PP * CC; idx += 256) {
        int r = idx / CC, c = idx - r * CC;
        sW1[r * W1S + c] = W1[idx];
    }

    const int g = tid / 25;          // team within block
    const int i = tid - g * 25;      // role: hidden unit index (0..24 always)
    const int n = blockIdx.x * TEAMS + g;
    const bool active = (g < TEAMS) && (n < NSEQ);

    // ---- per-role weights into registers (indices in-bounds for ALL threads) ----
    float wih_r[PP], wih_z[PP], wih_n[PP];
    #pragma unroll
    for (int p = 0; p < PP; ++p) {
        wih_r[p] = Wih[(     i) * PP + p];
        wih_z[p] = Wih[(25 + i) * PP + p];
        wih_n[p] = Wih[(50 + i) * PP + p];
    }
    float whh_r[HH], whh_z[HH], whh_n[HH];
    #pragma unroll
    for (int j = 0; j < HH; ++j) {
        whh_r[j] = Whh[(     i) * HH + j];
        whh_z[j] = Whh[(25 + i) * HH + j];
        whh_n[j] = Whh[(50 + i) * HH + j];
    }
    // combined biases for r,z (their x- and h-sides just add); separate for n
    const float b_r  = bih[i]      + bhh[i];
    const float b_z  = bih[25 + i] + bhh[25 + i];
    const float b_xn = bih[50 + i];
    const float b_hn = bhh[50 + i];

    const float* xp = x + (size_t)(active ? n : 0) * (TT * CC);
    float h_i = 0.f;
    float xv = active ? xp[i] : 0.f;   // prefetched x[n, t=0, i]

    __syncthreads();   // weights + h-init visible

    int cur = 0;
    for (int t = 0; t < TT; ++t) {
        // stage x[n,t,:] (one element per role)
        if (active) sx[g * XS + i] = xv;
        __syncthreads();                       // B1

        // prefetch next timestep's x while computing
        if (active && (t + 1 < TT)) xv = xp[(t + 1) * CC + i];

        // projection: p = LeakyReLU(W1 @ x + b1), roles 0..19
        if (active && i < PP) {
            const float4* w4 = (const float4*)(sW1 + i * W1S);
            const float4* x4 = (const float4*)(sx + g * XS);
            float wr[28], xr_[28];
            #pragma unroll
            for (int k = 0; k < 7; ++k) {
                float4 a = w4[k], b = x4[k];
                wr[4*k+0] = a.x; wr[4*k+1] = a.y; wr[4*k+2] = a.z; wr[4*k+3] = a.w;
                xr_[4*k+0] = b.x; xr_[4*k+1] = b.y; xr_[4*k+2] = b.z; xr_[4*k+3] = b.w;
            }
            float acc = sb1[i];
            #pragma unroll
            for (int c = 0; c < CC; ++c) acc += wr[c] * xr_[c];
            acc = (acc >= 0.f) ? acc : 0.01f * acc;
            sp[g * PS + i] = acc;
        }
        __syncthreads();                       // B2

        if (active) {
            // load p (20) and h (25) rows via float4
            float preg[PP];
            {
                const float4* p4 = (const float4*)(sp + g * PS);
                #pragma unroll
                for (int k = 0; k < 5; ++k) {
                    float4 v = p4[k];
                    preg[4*k+0] = v.x; preg[4*k+1] = v.y;
                    preg[4*k+2] = v.z; preg[4*k+3] = v.w;
                }
            }
            float hreg[28];
            {
                const float4* h4 = (const float4*)(sh[cur] + g * HS);
                #pragma unroll
                for (int k = 0; k < 7; ++k) {
                    float4 v = h4[k];
                    hreg[4*k+0] = v.x; hreg[4*k+1] = v.y;
                    hreg[4*k+2] = v.z; hreg[4*k+3] = v.w;
                }
            }
            float a_r = b_r, a_z = b_z, a_xn = b_xn, a_hn = b_hn;
            #pragma unroll
            for (int p = 0; p < PP; ++p) {
                const float pv = preg[p];
                a_r  += wih_r[p] * pv;
                a_z  += wih_z[p] * pv;
                a_xn += wih_n[p] * pv;
            }
            #pragma unroll
            for (int j = 0; j < HH; ++j) {
                const float hv = hreg[j];
                a_r  += whh_r[j] * hv;
                a_z  += whh_z[j] * hv;
                a_hn += whh_n[j] * hv;
            }
            const float r = 1.f / (1.f + __expf(-a_r));
            const float z = 1.f / (1.f + __expf(-a_z));
            const float a = a_xn + r * a_hn;
            const float nn = 2.f / (1.f + __expf(-2.f * a)) - 1.f;  // tanh(a)
            const float hnew = (1.f - z) * nn + z * h_i;
            h_i = hnew;
            sh[cur ^ 1][g * HS + i] = hnew;
        }
        cur ^= 1;
        // Next iteration's B1/B2 provide all needed ordering (see R1 note).
    }

    if (active) out[(size_t)n * HH + i] = h_i;
}

extern "C" void kernel_launch(void* const* d_in, const int* in_sizes, int n_in,
                              void* d_out, int out_size, void* d_ws, size_t ws_size,
                              hipStream_t stream) {
    const float* x   = (const float*)d_in[0];
    const float* W1  = (const float*)d_in[1];
    const float* b1  = (const float*)d_in[2];
    const float* Wih = (const float*)d_in[3];
    const float* Whh = (const float*)d_in[4];
    const float* bih = (const float*)d_in[5];
    const float* bhh = (const float*)d_in[6];
    float* out = (float*)d_out;

    const int nblocks = (NSEQ + TEAMS - 1) / TEAMS;   // 1639
    gru_fused<<<nblocks, 256, 0, stream>>>(x, W1, b1, Wih, Whh, bih, bhh, out);
}

// Round 3
// 508.562 us; speedup vs baseline: 2.0754x; 1.6440x over previous
//
#include <hip/hip_runtime.h>

// FeatureExtractor via MFMA bf16 (hi/lo split for fp32-level accuracy).
// x[32,512,128,25] -> Linear(25->20)+LeakyReLU -> Linear(20->75) -> GRU(H=25,T=128) -> h_T
//
// One 64-thread (single-wave) block per 16 sequences: 1024 blocks.
// Weights live in VGPRs as MFMA B-fragments. Gates use a padded-32-per-gate
// column layout (6 N-tiles of 16): r=[t0,t1], z=[t2,t3], n=[t4,t5], so the
// same lane holds r/z/xn/hn of the same (seq,unit) across acc tiles ->
// gate nonlinearity entirely in registers. h_old kept in C-layout registers.
// LDS only for the p and h A-fragment re-layouts (~4 KB).
//
// MFMA layouts (HW-verified per guide): A[m=lane&15][k=(lane>>4)*8+j],
// B[k=(lane>>4)*8+j][n=lane&15], D col=lane&15, row=(lane>>4)*4+reg.

typedef __bf16 bf16x8 __attribute__((ext_vector_type(8)));
typedef float  f32x4  __attribute__((ext_vector_type(4)));

#define TT 128
#define CC 25
#define PP 20
#define HH 25
#define NSEQ 16384

#define SPS 28   // p row stride (floats): 112 B, 16B-aligned, 2-way banks max
#define SHS 36   // h row stride (floats): 144 B, room for k=24..31 reads

__device__ __forceinline__ void split2(float f, __bf16& hi, __bf16& lo) {
    hi = (__bf16)f;
    lo = (__bf16)(f - (float)hi);
}

__device__ __forceinline__ float sigm(float v) {
    return 1.f / (1.f + __expf(-v));
}

__global__ __launch_bounds__(64, 1) void gru_mfma(
    const float* __restrict__ x,   const float* __restrict__ W1,
    const float* __restrict__ b1,  const float* __restrict__ Wih,
    const float* __restrict__ Whh, const float* __restrict__ bih,
    const float* __restrict__ bhh, float* __restrict__ out)
{
    __shared__ float sp[16 * SPS];
    __shared__ float sh[16 * SHS];

    const int lane = threadIdx.x;        // 0..63 (single wave)
    const int m    = lane & 15;
    const int q    = lane >> 4;
    const int n0   = blockIdx.x * 16;

    // zero LDS incl. pads (pads must stay 0 for A-frag reads)
    for (int idx = lane; idx < 16 * SPS; idx += 64) sp[idx] = 0.f;
    for (int idx = lane; idx < 16 * SHS; idx += 64) sh[idx] = 0.f;

    // ---- weight B-fragments into registers ----
    // tiles tt=0..5: gate=tt>>1 (0=r,1=z,2=n), unit u=(tt&1)*16 + (lane&15)
    bf16x8 whhH[6], whhL[6], wihH[6], wihL[6], w1H[2], w1L[2];
    #pragma unroll
    for (int tt = 0; tt < 6; ++tt) {
        const int gate = tt >> 1;
        const int u    = (tt & 1) * 16 + m;
        const bool gv  = (u < HH);
        const int grow = gate * HH + u;
        bf16x8 hh, hl, ih, il;
        #pragma unroll
        for (int j = 0; j < 8; ++j) {
            const int k = q * 8 + j;
            const float vhh = (gv && k < HH) ? Whh[grow * HH + k] : 0.f;
            const float vih = (gv && k < PP) ? Wih[grow * PP + k] : 0.f;
            __bf16 a, b;
            split2(vhh, a, b); hh[j] = a; hl[j] = b;
            split2(vih, a, b); ih[j] = a; il[j] = b;
        }
        whhH[tt] = hh; whhL[tt] = hl; wihH[tt] = ih; wihL[tt] = il;
    }
    #pragma unroll
    for (int tt = 0; tt < 2; ++tt) {
        const int n  = tt * 16 + m;
        const bool nv = (n < PP);
        bf16x8 h8, l8;
        #pragma unroll
        for (int j = 0; j < 8; ++j) {
            const int k = q * 8 + j;
            const float v = (nv && k < CC) ? W1[n * CC + k] : 0.f;
            __bf16 a, b; split2(v, a, b); h8[j] = a; l8[j] = b;
        }
        w1H[tt] = h8; w1L[tt] = l8;
    }

    // per-lane biases (tp: i = tp*16 + m)
    float br[2], bz[2], bxn[2], bhn[2], pb[2];
    #pragma unroll
    for (int tp = 0; tp < 2; ++tp) {
        const int i  = tp * 16 + m;
        const bool iv = (i < HH);
        br[tp]  = iv ? (bih[i] + bhh[i]) : 0.f;
        bz[tp]  = iv ? (bih[HH + i] + bhh[HH + i]) : 0.f;
        bxn[tp] = iv ? bih[2 * HH + i] : 0.f;
        bhn[tp] = iv ? bhh[2 * HH + i] : 0.f;
        pb[tp]  = (i < PP) ? b1[i] : 0.f;
    }

    float ho[2][4] = {{0.f,0.f,0.f,0.f},{0.f,0.f,0.f,0.f}};  // h0 = 0

    const float* xrow = x + (size_t)(n0 + m) * TT * CC;

    // x A-frag prefetch for t=0 (lane: seq m, channels q*8..q*8+7)
    float xc[8];
    #pragma unroll
    for (int j = 0; j < 8; ++j) {
        const int k = q * 8 + j;
        xc[j] = (k < CC) ? xrow[k] : 0.f;
    }

    __syncthreads();

    for (int t = 0; t < TT; ++t) {
        __syncthreads();   // orders prev-step h writes before this step's reads

        // prefetch next timestep's x
        float xnx[8];
        #pragma unroll
        for (int j = 0; j < 8; ++j) xnx[j] = 0.f;
        if (t + 1 < TT) {
            const float* xr = xrow + (t + 1) * CC;
            #pragma unroll
            for (int j = 0; j < 8; ++j) {
                const int k = q * 8 + j;
                if (k < CC) xnx[j] = xr[k];
            }
        }

        // ---- proj: p = leaky(x @ W1^T + b1) ----
        bf16x8 xH, xL;
        #pragma unroll
        for (int j = 0; j < 8; ++j) { __bf16 a,b; split2(xc[j], a, b); xH[j]=a; xL[j]=b; }

        f32x4 p0 = {0.f,0.f,0.f,0.f}, p1 = {0.f,0.f,0.f,0.f};
        p0 = __builtin_amdgcn_mfma_f32_16x16x32_bf16(xH, w1H[0], p0, 0,0,0);
        p0 = __builtin_amdgcn_mfma_f32_16x16x32_bf16(xH, w1L[0], p0, 0,0,0);
        p0 = __builtin_amdgcn_mfma_f32_16x16x32_bf16(xL, w1H[0], p0, 0,0,0);
        p1 = __builtin_amdgcn_mfma_f32_16x16x32_bf16(xH, w1H[1], p1, 0,0,0);
        p1 = __builtin_amdgcn_mfma_f32_16x16x32_bf16(xH, w1L[1], p1, 0,0,0);
        p1 = __builtin_amdgcn_mfma_f32_16x16x32_bf16(xL, w1H[1], p1, 0,0,0);

        #pragma unroll
        for (int r = 0; r < 4; ++r) {
            const int mrow = 4 * q + r;
            float v = p0[r] + pb[0];
            v = (v >= 0.f) ? v : 0.01f * v;
            sp[mrow * SPS + m] = v;
            if (m < PP - 16) {           // cols 16..19
                float w = p1[r] + pb[1];
                w = (w >= 0.f) ? w : 0.01f * w;
                sp[mrow * SPS + 16 + m] = w;
            }
        }
        __syncthreads();

        // ---- p and h A-fragments ----
        bf16x8 pH, pL;
        if (q < 3) {
            const f32x4* pr = (const f32x4*)(sp + m * SPS + q * 8);
            const f32x4 a = pr[0], b = pr[1];
            const float tmp[8] = {a[0],a[1],a[2],a[3],b[0],b[1],b[2],b[3]};
            #pragma unroll
            for (int j = 0; j < 8; ++j) { __bf16 hi,lo; split2(tmp[j],hi,lo); pH[j]=hi; pL[j]=lo; }
        } else {
            #pragma unroll
            for (int j = 0; j < 8; ++j) { pH[j] = (__bf16)0.f; pL[j] = (__bf16)0.f; }
        }

        bf16x8 hH, hL;
        {
            const f32x4* hr = (const f32x4*)(sh + m * SHS + q * 8);
            const f32x4 a = hr[0], b = hr[1];
            const float tmp[8] = {a[0],a[1],a[2],a[3],b[0],b[1],b[2],b[3]};
            #pragma unroll
            for (int j = 0; j < 8; ++j) { __bf16 hi,lo; split2(tmp[j],hi,lo); hH[j]=hi; hL[j]=lo; }
        }

        // ---- gate pre-activations ----
        f32x4 aR[2], aZ[2], aXN[2], aHN[2];
        #pragma unroll
        for (int tp = 0; tp < 2; ++tp) {
            f32x4 acc = {0.f,0.f,0.f,0.f};
            // r: x-side + h-side combined
            acc = __builtin_amdgcn_mfma_f32_16x16x32_bf16(pH, wihH[tp], acc, 0,0,0);
            acc = __builtin_amdgcn_mfma_f32_16x16x32_bf16(pH, wihL[tp], acc, 0,0,0);
            acc = __builtin_amdgcn_mfma_f32_16x16x32_bf16(pL, wihH[tp], acc, 0,0,0);
            acc = __builtin_amdgcn_mfma_f32_16x16x32_bf16(hH, whhH[tp], acc, 0,0,0);
            acc = __builtin_amdgcn_mfma_f32_16x16x32_bf16(hH, whhL[tp], acc, 0,0,0);
            acc = __builtin_amdgcn_mfma_f32_16x16x32_bf16(hL, whhH[tp], acc, 0,0,0);
            aR[tp] = acc;
            f32x4 accz = {0.f,0.f,0.f,0.f};
            accz = __builtin_amdgcn_mfma_f32_16x16x32_bf16(pH, wihH[2+tp], accz, 0,0,0);
            accz = __builtin_amdgcn_mfma_f32_16x16x32_bf16(pH, wihL[2+tp], accz, 0,0,0);
            accz = __builtin_amdgcn_mfma_f32_16x16x32_bf16(pL, wihH[2+tp], accz, 0,0,0);
            accz = __builtin_amdgcn_mfma_f32_16x16x32_bf16(hH, whhH[2+tp], accz, 0,0,0);
            accz = __builtin_amdgcn_mfma_f32_16x16x32_bf16(hH, whhL[2+tp], accz, 0,0,0);
            accz = __builtin_amdgcn_mfma_f32_16x16x32_bf16(hL, whhH[2+tp], accz, 0,0,0);
            aZ[tp] = accz;
            f32x4 accx = {0.f,0.f,0.f,0.f};  // xn: x-side only
            accx = __builtin_amdgcn_mfma_f32_16x16x32_bf16(pH, wihH[4+tp], accx, 0,0,0);
            accx = __builtin_amdgcn_mfma_f32_16x16x32_bf16(pH, wihL[4+tp], accx, 0,0,0);
            accx = __builtin_amdgcn_mfma_f32_16x16x32_bf16(pL, wihH[4+tp], accx, 0,0,0);
            aXN[tp] = accx;
            f32x4 acch = {0.f,0.f,0.f,0.f};  // hn: h-side only
            acch = __builtin_amdgcn_mfma_f32_16x16x32_bf16(hH, whhH[4+tp], acch, 0,0,0);
            acch = __builtin_amdgcn_mfma_f32_16x16x32_bf16(hH, whhL[4+tp], acch, 0,0,0);
            acch = __builtin_amdgcn_mfma_f32_16x16x32_bf16(hL, whhH[4+tp], acch, 0,0,0);
            aHN[tp] = acch;
        }

        // ---- gate nonlinearity entirely in registers ----
        #pragma unroll
        for (int tp = 0; tp < 2; ++tp) {
            #pragma unroll
            for (int r = 0; r < 4; ++r) {
                const float ar = aR[tp][r]  + br[tp];
                const float az = aZ[tp][r]  + bz[tp];
                const float an = aXN[tp][r] + bxn[tp];
                const float ah = aHN[tp][r] + bhn[tp];
                const float rg = sigm(ar);
                const float zg = sigm(az);
                const float tv = an + rg * ah;
                const float e  = __expf(-2.f * tv);
                const float ng = 2.f / (1.f + e) - 1.f;        // tanh
                const float hn_ = zg * (ho[tp][r] - ng) + ng;   // (1-z)n + z h
                ho[tp][r] = hn_;
            }
        }

        // write h_new to LDS rows for next step's A-frags
        #pragma unroll
        for (int tp = 0; tp < 2; ++tp) {
            if (tp == 0 || m < HH - 16) {
                #pragma unroll
                for (int r = 0; r < 4; ++r)
                    sh[(4 * q + r) * SHS + tp * 16 + m] = ho[tp][r];
            }
        }

        #pragma unroll
        for (int j = 0; j < 8; ++j) xc[j] = xnx[j];
    }

    // ---- epilogue: h_T in C-layout -> out[n0+4q+r][i] ----
    #pragma unroll
    for (int tp = 0; tp < 2; ++tp) {
        if (tp == 0 || m < HH - 16) {
            #pragma unroll
            for (int r = 0; r < 4; ++r)
                out[(size_t)(n0 + 4 * q + r) * HH + tp * 16 + m] = ho[tp][r];
        }
    }
}

extern "C" void kernel_launch(void* const* d_in, const int* in_sizes, int n_in,
                              void* d_out, int out_size, void* d_ws, size_t ws_size,
                              hipStream_t stream) {
    const float* x   = (const float*)d_in[0];
    const float* W1  = (const float*)d_in[1];
    const float* b1  = (const float*)d_in[2];
    const float* Wih = (const float*)d_in[3];
    const float* Whh = (const float*)d_in[4];
    const float* bih = (const float*)d_in[5];
    const float* bhh = (const float*)d_in[6];
    float* out = (float*)d_out;

    gru_mfma<<<NSEQ / 16, 64, 0, stream>>>(x, W1, b1, Wih, Whh, bih, bhh, out);
}

// Round 4
// 429.792 us; speedup vs baseline: 2.4558x; 1.1833x over previous
//
#include <hip/hip_runtime.h>

// FeatureExtractor via MFMA bf16 hi/lo, TRANSPOSED orientation, barrier-free.
// x[32,512,128,25] -> Linear(25->20)+LeakyReLU -> Linear(20->75) -> GRU(H=25,T=128)
// One single-wave block per 16 sequences (1024 blocks). No __syncthreads in the
// loop: single wave => in-wave-ordered LDS + compiler lgkmcnt suffice; keeps the
// scattered x prefetch loads in flight across the whole step (R3's 2 barriers
// drained vmcnt(0) every step => ~900cyc HBM latency serialized per step).
//
// Transposed MFMA: A = weights (row=unit), B = activations (col=seq),
// D[row=unit 4q+r][col=seq m]. Biases folded into MFMA via constant-1.0
// channels: p row ch20=1, h row ch25=1, x frag k25=1; weight frags carry
// bih/bhh/b1 at those k positions. Zero bias adds in the loop.
// Layouts per verified guide mapping: A[m][k]/B[k][n]: m|n=lane&15,
// k=(lane>>4)*8+j; D: col=lane&15, row=(lane>>4)*4+reg.

typedef __bf16 bf16x8 __attribute__((ext_vector_type(8)));
typedef float  f32x4  __attribute__((ext_vector_type(4)));

#define TT 128
#define CC 25
#define PP 20
#define HH 25
#define NSEQ 16384
#define S  36          // LDS row stride (floats); rows 16B-aligned, 2-way banks max

__device__ __forceinline__ void split2(float f, __bf16& hi, __bf16& lo) {
    hi = (__bf16)f;
    lo = (__bf16)(f - (float)hi);
}
__device__ __forceinline__ float sigm(float v) { return 1.f / (1.f + __expf(-v)); }

__global__ __launch_bounds__(64, 1) void gru_mfma_t(
    const float* __restrict__ x,   const float* __restrict__ W1,
    const float* __restrict__ b1,  const float* __restrict__ Wih,
    const float* __restrict__ Whh, const float* __restrict__ bih,
    const float* __restrict__ bhh, float* __restrict__ out)
{
    __shared__ float sp[16 * S];        // p rows: ch0-19 p, ch20 = 1.0 (bias), 21-31 = 0
    __shared__ float sh[2][16 * S];     // h rows: ch0-24 h, ch25 = 1.0 (bias), 26-31 = 0

    const int lane = threadIdx.x;
    const int m = lane & 15, q = lane >> 4;
    const int n0 = blockIdx.x * 16;

    // ---- LDS init: zeros + bias channels ----
    for (int idx = lane; idx < 16 * S; idx += 64) {
        sp[idx] = 0.f; sh[0][idx] = 0.f; sh[1][idx] = 0.f;
    }
    __syncthreads();
    if (lane < 16) {
        sp[lane * S + PP]    = 1.0f;
        sh[0][lane * S + HH] = 1.0f;
        sh[1][lane * S + HH] = 1.0f;
    }
    __syncthreads();   // once, outside the loop

    // ---- weight A-fragments (rows = units, k = channels; bias at k==PP/HH/CC) ----
    bf16x8 WihH[6], WihL[6], WhhH[6], WhhL[6], W1H[2], W1L[2];
    #pragma unroll
    for (int tt = 0; tt < 6; ++tt) {
        const int g = tt >> 1;                 // 0=r,1=z,2=n
        const int u = (tt & 1) * 16 + m;       // unit within gate
        const bool uv = (u < HH);
        const int row = g * HH + u;
        bf16x8 ih, il, hh, hl;
        #pragma unroll
        for (int j = 0; j < 8; ++j) {
            const int k = q * 8 + j;
            float vih = 0.f, vhh = 0.f;
            if (uv) {
                if (k < PP)       vih = Wih[row * PP + k];
                else if (k == PP) vih = bih[row];
                if (k < HH)       vhh = Whh[row * HH + k];
                else if (k == HH) vhh = bhh[row];
            }
            __bf16 a, b;
            split2(vih, a, b); ih[j] = a; il[j] = b;
            split2(vhh, a, b); hh[j] = a; hl[j] = b;
        }
        WihH[tt] = ih; WihL[tt] = il; WhhH[tt] = hh; WhhL[tt] = hl;
    }
    #pragma unroll
    for (int tt = 0; tt < 2; ++tt) {
        const int u = tt * 16 + m;
        const bool uv = (u < PP);
        bf16x8 h8, l8;
        #pragma unroll
        for (int j = 0; j < 8; ++j) {
            const int k = q * 8 + j;
            float v = 0.f;
            if (uv) {
                if (k < CC)       v = W1[u * CC + k];
                else if (k == CC) v = b1[u];
            }
            __bf16 a, b; split2(v, a, b); h8[j] = a; l8[j] = b;
        }
        W1H[tt] = h8; W1L[tt] = l8;
    }

    // ---- x B-fragment prefetch (lane: seq m, channels q*8..q*8+7; k==CC -> 1.0) ----
    const float* xrow = x + (size_t)(n0 + m) * (TT * CC);
    float xc[8];
    #pragma unroll
    for (int j = 0; j < 8; ++j) {
        const int k = q * 8 + j;
        xc[j] = (k < CC) ? xrow[k] : (k == CC ? 1.0f : 0.f);
    }

    float ho[2][4] = {{0.f,0.f,0.f,0.f},{0.f,0.f,0.f,0.f}};

    for (int t = 0; t < TT; ++t) {
        // split current x
        bf16x8 xH, xL;
        #pragma unroll
        for (int j = 0; j < 8; ++j) { __bf16 a,b; split2(xc[j],a,b); xH[j]=a; xL[j]=b; }

        // prefetch next x (stays in flight ~one full step; k>=CC slots keep bias/0)
        if (t + 1 < TT) {
            const float* xr = xrow + (t + 1) * CC;
            #pragma unroll
            for (int j = 0; j < 8; ++j) {
                const int k = q * 8 + j;
                if (k < CC) xc[j] = xr[k];
            }
        }

        // ---- proj: P[unit][seq] = W1aug * [x;1]  (3-term hi/lo) ----
        f32x4 p0 = {0.f,0.f,0.f,0.f}, p1 = {0.f,0.f,0.f,0.f};
        p0 = __builtin_amdgcn_mfma_f32_16x16x32_bf16(W1H[0], xH, p0, 0,0,0);
        p0 = __builtin_amdgcn_mfma_f32_16x16x32_bf16(W1H[0], xL, p0, 0,0,0);
        p0 = __builtin_amdgcn_mfma_f32_16x16x32_bf16(W1L[0], xH, p0, 0,0,0);
        p1 = __builtin_amdgcn_mfma_f32_16x16x32_bf16(W1H[1], xH, p1, 0,0,0);
        p1 = __builtin_amdgcn_mfma_f32_16x16x32_bf16(W1H[1], xL, p1, 0,0,0);
        p1 = __builtin_amdgcn_mfma_f32_16x16x32_bf16(W1L[1], xH, p1, 0,0,0);

        #pragma unroll
        for (int r = 0; r < 4; ++r) {
            p0[r] = (p0[r] >= 0.f) ? p0[r] : 0.01f * p0[r];
            p1[r] = (p1[r] >= 0.f) ? p1[r] : 0.01f * p1[r];
        }

        // p -> LDS (units 4q..4q+3 of seq m); tile1 only valid for q==0 (units 16-19)
        *(f32x4*)(sp + m * S + 4 * q) = p0;
        if (q == 0) *(f32x4*)(sp + m * S + 16) = p1;

        // ---- read B-fragments: p (ch 8q..8q+7 incl bias/pad) and h ----
        f32x4 pa = ((const f32x4*)(sp + m * S + 8 * q))[0];
        f32x4 pb = ((const f32x4*)(sp + m * S + 8 * q))[1];
        bf16x8 pH, pL;
        #pragma unroll
        for (int j = 0; j < 4; ++j) {
            __bf16 a,b;
            split2(pa[j], a, b); pH[j]   = a; pL[j]   = b;
            split2(pb[j], a, b); pH[4+j] = a; pL[4+j] = b;
        }
        f32x4 ha = ((const f32x4*)(sh[t & 1] + m * S + 8 * q))[0];
        f32x4 hb = ((const f32x4*)(sh[t & 1] + m * S + 8 * q))[1];
        bf16x8 hH, hL;
        #pragma unroll
        for (int j = 0; j < 4; ++j) {
            __bf16 a,b;
            split2(ha[j], a, b); hH[j]   = a; hL[j]   = b;
            split2(hb[j], a, b); hH[4+j] = a; hL[4+j] = b;
        }

        // ---- gates: D[unit][seq], biases folded via constant-1 channels ----
        f32x4 aR[2], aZ[2], aN[2], aHn[2];
        #pragma unroll
        for (int tp = 0; tp < 2; ++tp) {
            f32x4 acc = {0.f,0.f,0.f,0.f};
            acc = __builtin_amdgcn_mfma_f32_16x16x32_bf16(WihH[tp], pH, acc, 0,0,0);
            acc = __builtin_amdgcn_mfma_f32_16x16x32_bf16(WihH[tp], pL, acc, 0,0,0);
            acc = __builtin_amdgcn_mfma_f32_16x16x32_bf16(WihL[tp], pH, acc, 0,0,0);
            acc = __builtin_amdgcn_mfma_f32_16x16x32_bf16(WhhH[tp], hH, acc, 0,0,0);
            acc = __builtin_amdgcn_mfma_f32_16x16x32_bf16(WhhH[tp], hL, acc, 0,0,0);
            acc = __builtin_amdgcn_mfma_f32_16x16x32_bf16(WhhL[tp], hH, acc, 0,0,0);
            aR[tp] = acc;
            f32x4 az = {0.f,0.f,0.f,0.f};
            az = __builtin_amdgcn_mfma_f32_16x16x32_bf16(WihH[2+tp], pH, az, 0,0,0);
            az = __builtin_amdgcn_mfma_f32_16x16x32_bf16(WihH[2+tp], pL, az, 0,0,0);
            az = __builtin_amdgcn_mfma_f32_16x16x32_bf16(WihL[2+tp], pH, az, 0,0,0);
            az = __builtin_amdgcn_mfma_f32_16x16x32_bf16(WhhH[2+tp], hH, az, 0,0,0);
            az = __builtin_amdgcn_mfma_f32_16x16x32_bf16(WhhH[2+tp], hL, az, 0,0,0);
            az = __builtin_amdgcn_mfma_f32_16x16x32_bf16(WhhL[2+tp], hH, az, 0,0,0);
            aZ[tp] = az;
            f32x4 an = {0.f,0.f,0.f,0.f};
            an = __builtin_amdgcn_mfma_f32_16x16x32_bf16(WihH[4+tp], pH, an, 0,0,0);
            an = __builtin_amdgcn_mfma_f32_16x16x32_bf16(WihH[4+tp], pL, an, 0,0,0);
            an = __builtin_amdgcn_mfma_f32_16x16x32_bf16(WihL[4+tp], pH, an, 0,0,0);
            aN[tp] = an;
            f32x4 ah = {0.f,0.f,0.f,0.f};
            ah = __builtin_amdgcn_mfma_f32_16x16x32_bf16(WhhH[4+tp], hH, ah, 0,0,0);
            ah = __builtin_amdgcn_mfma_f32_16x16x32_bf16(WhhH[4+tp], hL, ah, 0,0,0);
            ah = __builtin_amdgcn_mfma_f32_16x16x32_bf16(WhhL[4+tp], hH, ah, 0,0,0);
            aHn[tp] = ah;
        }

        // ---- nonlinearity (no bias adds) + h update + store to next buffer ----
        #pragma unroll
        for (int tp = 0; tp < 2; ++tp) {
            f32x4 hv;
            #pragma unroll
            for (int r = 0; r < 4; ++r) {
                const float rg = sigm(aR[tp][r]);
                const float zg = sigm(aZ[tp][r]);
                const float nv = aN[tp][r] + rg * aHn[tp][r];
                const float e  = __expf(-2.f * nv);
                const float ng = 2.f / (1.f + e) - 1.f;          // tanh
                const float h2 = zg * (ho[tp][r] - ng) + ng;     // (1-z)n + z h
                ho[tp][r] = h2; hv[r] = h2;
            }
            float* dst = sh[(t + 1) & 1] + m * S + tp * 16 + 4 * q;
            if (tp == 0) {
                *(f32x4*)dst = hv;
            } else {
                if (q < 2)       *(f32x4*)dst = hv;     // units 16-23
                else if (q == 2) dst[0] = hv[0];        // unit 24 (25-27 stay pad)
            }
        }
    }

    // ---- epilogue: out[seq][unit] ----
    float* orow = out + (size_t)(n0 + m) * HH;
    #pragma unroll
    for (int tp = 0; tp < 2; ++tp) {
        #pragma unroll
        for (int r = 0; r < 4; ++r) {
            const int u = tp * 16 + 4 * q + r;
            if (u < HH) orow[u] = ho[tp][r];
        }
    }
}

extern "C" void kernel_launch(void* const* d_in, const int* in_sizes, int n_in,
                              void* d_out, int out_size, void* d_ws, size_t ws_size,
                              hipStream_t stream) {
    const float* x   = (const float*)d_in[0];
    const float* W1  = (const float*)d_in[1];
    const float* b1  = (const float*)d_in[2];
    const float* Wih = (const float*)d_in[3];
    const float* Whh = (const float*)d_in[4];
    const float* bih = (const float*)d_in[5];
    const float* bhh = (const float*)d_in[6];
    float* out = (float*)d_out;

    gru_mfma_t<<<NSEQ / 16, 64, 0, stream>>>(x, W1, b1, Wih, Whh, bih, bhh, out);
}